// Round 2
// baseline (537.556 us; speedup 1.0000x reference)
//
#include <hip/hip_runtime.h>

#define NN 100000
#define EE 3200000
#define FIN 128
#define HID 16
#define NC 8
#define NX 8   // XCDs on MI355X

// Physical XCD id of this wave's CU (wave-uniform). [measured: learn_hip m09]
__device__ __forceinline__ unsigned xcc_id() {
    unsigned x;
    asm("s_getreg_b32 %0, hwreg(HW_REG_XCC_ID)" : "=s"(x));
    return x & 7u;
}

// Workgroup-scope atomic on global memory: lowers to global_atomic_add without
// sc1 -> executes in the LOCAL XCD L2 (no write-through to memory side).
// Correct here because each XCD only touches its own private copy, and the
// kernel-end implicit release writes L2 back for the next kernel.
__device__ __forceinline__ void atom_add_l2(float* p, float v) {
    __hip_atomic_fetch_add(p, v, __ATOMIC_RELAXED, __HIP_MEMORY_SCOPE_WORKGROUP);
}

// ---- zero a float4 region (grid-stride) ----
__global__ __launch_bounds__(256) void k_zero(float4* __restrict__ p, int n4) {
    int i = blockIdx.x * 256 + threadIdx.x;
    int stride = gridDim.x * 256;
    for (; i < n4; i += stride) p[i] = float4{0.f, 0.f, 0.f, 0.f};
}

// ---- degree histogram into per-XCD copies ----
__global__ __launch_bounds__(256) void k_deg_acc(const int* __restrict__ col,
                                                 float* __restrict__ degc) {
    int e = blockIdx.x * 256 + threadIdx.x;
    if (e >= EE) return;
    unsigned x = xcc_id();
    atom_add_l2(&degc[x * NN + col[e]], 1.0f);
}

// ---- dinv[i] = rsqrt(1 + sum of copies) ----
__global__ __launch_bounds__(256) void k_dinv(const float* __restrict__ degc,
                                              float* __restrict__ dinv) {
    int i = blockIdx.x * 256 + threadIdx.x;
    if (i >= NN) return;
    float d = 1.0f;
    #pragma unroll
    for (int x = 0; x < NX; ++x) d += degc[x * NN + i];
    dinv[i] = rsqrtf(d);
}

// ---- layer 1 transform: hs1 = (x @ W1) * dinv ----
__global__ __launch_bounds__(256) void k_gemm1(const float* __restrict__ x,
                                               const float* __restrict__ W1,
                                               const float* __restrict__ dinv,
                                               float* __restrict__ hs1) {
    __shared__ float w1s[FIN * HID];   // 8 KB
    __shared__ float xs[64 * 132];     // 64 rows, stride 132 (pad) ~34 KB
    int t = threadIdx.x;
    int r0 = blockIdx.x * 64;
    for (int i = t; i < FIN * HID; i += 256) w1s[i] = W1[i];
    int maxr = NN - r0; if (maxr > 64) maxr = 64;
    const float4* x4 = reinterpret_cast<const float4*>(x + (size_t)r0 * FIN);
    #pragma unroll
    for (int i = 0; i < 8; ++i) {
        int fi = t + i * 256;          // float4 index in tile, 0..2047
        int f = fi * 4;
        int row = f >> 7, k = f & 127;
        if (row < maxr) {
            float4 v = x4[fi];
            *reinterpret_cast<float4*>(&xs[row * 132 + k]) = v;
        }
    }
    __syncthreads();
    int row = t >> 2;
    int cg = (t & 3) * 4;
    if (row < maxr) {
        float4 acc = {0.f, 0.f, 0.f, 0.f};
        const float* xr = &xs[row * 132];
        #pragma unroll 4
        for (int k = 0; k < FIN; ++k) {
            float xv = xr[k];
            const float4 w = *reinterpret_cast<const float4*>(&w1s[k * HID + cg]);
            acc.x += xv * w.x; acc.y += xv * w.y; acc.z += xv * w.z; acc.w += xv * w.w;
        }
        int r = r0 + row;
        float di = dinv[r];
        acc.x *= di; acc.y *= di; acc.z *= di; acc.w *= di;
        *reinterpret_cast<float4*>(&hs1[r * HID + cg]) = acc;
    }
}

// ---- layer 1 scatter into per-XCD copies: one thread per (edge, channel) ----
__global__ __launch_bounds__(256) void k_scatter1(const int* __restrict__ row,
                                                  const int* __restrict__ col,
                                                  const float* __restrict__ hs1,
                                                  float* __restrict__ aggc1) {
    int idx = blockIdx.x * 256 + threadIdx.x;   // < EE*16 = 51.2M
    int e = idx >> 4, c = idx & 15;
    int s = row[e], d = col[e];
    unsigned x = xcc_id();
    atom_add_l2(&aggc1[(size_t)x * NN * HID + d * HID + c], hs1[s * HID + c]);
}

// ---- finalize layer1 + transform layer2 ----
__global__ __launch_bounds__(256) void k_fin1(const float* __restrict__ aggc1,
                                              const float* __restrict__ hs1,
                                              const float* __restrict__ dinv,
                                              const float* __restrict__ W2,
                                              const float* __restrict__ b1,
                                              float* __restrict__ hs2) {
    __shared__ float w2s[HID * NC];
    __shared__ float b1s[HID];
    int t = threadIdx.x;
    if (t < HID * NC) w2s[t] = W2[t];
    if (t < HID) b1s[t] = b1[t];
    __syncthreads();
    int i = blockIdx.x * 256 + t;
    if (i >= NN) return;
    float di = dinv[i];
    float a[HID];
    {   // self-loop term: hs1[i]
        const float4* s4 = reinterpret_cast<const float4*>(hs1 + (size_t)i * HID);
        #pragma unroll
        for (int q = 0; q < 4; ++q) {
            float4 v = s4[q];
            a[q*4+0] = v.x; a[q*4+1] = v.y; a[q*4+2] = v.z; a[q*4+3] = v.w;
        }
    }
    #pragma unroll
    for (int x = 0; x < NX; ++x) {
        const float4* c4 = reinterpret_cast<const float4*>(aggc1 + (size_t)x * NN * HID + (size_t)i * HID);
        #pragma unroll
        for (int q = 0; q < 4; ++q) {
            float4 v = c4[q];
            a[q*4+0] += v.x; a[q*4+1] += v.y; a[q*4+2] += v.z; a[q*4+3] += v.w;
        }
    }
    float h[HID];
    #pragma unroll
    for (int k = 0; k < HID; ++k) h[k] = fmaxf(a[k] * di + b1s[k], 0.f);
    float o[NC];
    #pragma unroll
    for (int c = 0; c < NC; ++c) o[c] = 0.f;
    #pragma unroll
    for (int k = 0; k < HID; ++k) {
        float hv = h[k];
        #pragma unroll
        for (int c = 0; c < NC; ++c) o[c] += hv * w2s[k * NC + c];
    }
    float4 v0 = {o[0]*di, o[1]*di, o[2]*di, o[3]*di};
    float4 v1 = {o[4]*di, o[5]*di, o[6]*di, o[7]*di};
    float4* h2 = reinterpret_cast<float4*>(hs2 + (size_t)i * NC);
    h2[0] = v0; h2[1] = v1;
}

// ---- layer 2 scatter into per-XCD copies ----
__global__ __launch_bounds__(256) void k_scatter2(const int* __restrict__ row,
                                                  const int* __restrict__ col,
                                                  const float* __restrict__ hs2,
                                                  float* __restrict__ aggc2) {
    int idx = blockIdx.x * 256 + threadIdx.x;   // < EE*8 = 25.6M
    int e = idx >> 3, c = idx & 7;
    int s = row[e], d = col[e];
    unsigned x = xcc_id();
    atom_add_l2(&aggc2[(size_t)x * NN * NC + d * NC + c], hs2[s * NC + c]);
}

// ---- finalize layer2 + log_softmax ----
__global__ __launch_bounds__(256) void k_fin2(const float* __restrict__ aggc2,
                                              const float* __restrict__ hs2,
                                              const float* __restrict__ dinv,
                                              const float* __restrict__ b2,
                                              float* __restrict__ out) {
    __shared__ float b2s[NC];
    int t = threadIdx.x;
    if (t < NC) b2s[t] = b2[t];
    __syncthreads();
    int i = blockIdx.x * 256 + t;
    if (i >= NN) return;
    float di = dinv[i];
    float v[NC];
    {
        const float4* s4 = reinterpret_cast<const float4*>(hs2 + (size_t)i * NC);
        float4 u0 = s4[0], u1 = s4[1];
        v[0]=u0.x; v[1]=u0.y; v[2]=u0.z; v[3]=u0.w;
        v[4]=u1.x; v[5]=u1.y; v[6]=u1.z; v[7]=u1.w;
    }
    #pragma unroll
    for (int x = 0; x < NX; ++x) {
        const float4* c4 = reinterpret_cast<const float4*>(aggc2 + (size_t)x * NN * NC + (size_t)i * NC);
        float4 u0 = c4[0], u1 = c4[1];
        v[0]+=u0.x; v[1]+=u0.y; v[2]+=u0.z; v[3]+=u0.w;
        v[4]+=u1.x; v[5]+=u1.y; v[6]+=u1.z; v[7]+=u1.w;
    }
    #pragma unroll
    for (int c = 0; c < NC; ++c) v[c] = v[c] * di + b2s[c];
    float m = v[0];
    #pragma unroll
    for (int c = 1; c < NC; ++c) m = fmaxf(m, v[c]);
    float s = 0.f;
    #pragma unroll
    for (int c = 0; c < NC; ++c) s += expf(v[c] - m);
    float ls = logf(s);
    float4 o0 = {v[0]-m-ls, v[1]-m-ls, v[2]-m-ls, v[3]-m-ls};
    float4 o1 = {v[4]-m-ls, v[5]-m-ls, v[6]-m-ls, v[7]-m-ls};
    float4* op = reinterpret_cast<float4*>(out + (size_t)i * NC);
    op[0] = o0; op[1] = o1;
}

extern "C" void kernel_launch(void* const* d_in, const int* in_sizes, int n_in,
                              void* d_out, int out_size, void* d_ws, size_t ws_size,
                              hipStream_t stream) {
    const float* x   = (const float*)d_in[0];
    const int*   ei  = (const int*)d_in[1];     // [2, E]: row then col
    const float* W1  = (const float*)d_in[2];
    const float* b1  = (const float*)d_in[3];
    const float* W2  = (const float*)d_in[4];
    const float* b2  = (const float*)d_in[5];
    float* out = (float*)d_out;

    const int* row = ei;
    const int* col = ei + EE;

    // ws layout (floats):
    //   dinv   [NN]                          0.4 MB
    //   hs1    [NN*HID]                      6.4 MB
    //   hs2    [NN*NC]                       3.2 MB
    //   degc   [NX*NN]                       3.2 MB   (contiguous with aggc1 -> one zero pass)
    //   aggc1  [NX*NN*HID]                  51.2 MB   (aggc2 [NX*NN*NC] aliases its front half)
    float* ws    = (float*)d_ws;
    float* dinv  = ws;
    float* hs1   = dinv + NN;
    float* hs2   = hs1  + (size_t)NN * HID;
    float* degc  = hs2  + (size_t)NN * NC;
    float* aggc1 = degc + (size_t)NX * NN;
    float* aggc2 = aggc1;   // reuse after fin1 consumed aggc1

    const int nb_n = (NN + 255) / 256;

    // zero degc + aggc1 in one pass (contiguous): NX*NN*(1+HID) floats
    int n4_a = (int)((size_t)NX * NN * (1 + HID) / 4);
    k_zero<<<2048, 256, 0, stream>>>(reinterpret_cast<float4*>(degc), n4_a);
    k_deg_acc<<<(EE + 255) / 256, 256, 0, stream>>>(col, degc);
    k_dinv<<<nb_n, 256, 0, stream>>>(degc, dinv);
    k_gemm1<<<(NN + 63) / 64, 256, 0, stream>>>(x, W1, dinv, hs1);
    k_scatter1<<<(size_t)EE * HID / 256, 256, 0, stream>>>(row, col, hs1, aggc1);
    k_fin1<<<nb_n, 256, 0, stream>>>(aggc1, hs1, dinv, W2, b1, hs2);
    int n4_b = (int)((size_t)NX * NN * NC / 4);
    k_zero<<<2048, 256, 0, stream>>>(reinterpret_cast<float4*>(aggc2), n4_b);
    k_scatter2<<<(size_t)EE * NC / 256, 256, 0, stream>>>(row, col, hs2, aggc2);
    k_fin2<<<nb_n, 256, 0, stream>>>(aggc2, hs2, dinv, b2, out);
}